// Round 9
// baseline (258.246 us; speedup 1.0000x reference)
//
#include <hip/hip_runtime.h>
#include <math.h>

// ---------------------------------------------------------------------------
// RoutedAllFC round 9: 3-product fp16-split backbone (round 8 arithmetic),
// with the b1 low-plane spilled to global scratch (L2-resident) to cut LDS
// 50.7KB -> 32.3KB => 4 blocks/CU, 100% wave occupancy.
// Fallback to the LDS-resident variant if ws_size is too small.
// ---------------------------------------------------------------------------

#define IMG_B 4096

typedef _Float16 f16x8 __attribute__((ext_vector_type(8)));
typedef _Float16 f16x4 __attribute__((ext_vector_type(4)));
typedef float    f32x4 __attribute__((ext_vector_type(4)));

union U16x8 { unsigned u[4]; f16x8 v; };

__device__ inline f16x8 f16x8_zero() {
    f16x8 z;
    #pragma unroll
    for (int i = 0; i < 8; ++i) z[i] = (_Float16)0.f;
    return z;
}

// ---- weight prep: fp16 h/l split for all convs --------------------------
// w1s: [part][oc(32)][k(32)]  k = ic*9 + dy*3 + dx, k>=27 -> 0
// w2s/w3s/w4s: [tap][part][oc(32)][ic(32)]
__global__ __launch_bounds__(256) void twt_kernel(
    const float* __restrict__ cw1, const float* __restrict__ cw2,
    const float* __restrict__ cw3, const float* __restrict__ cw4,
    _Float16* __restrict__ w1s, _Float16* __restrict__ w2s,
    _Float16* __restrict__ w3s, _Float16* __restrict__ w4s)
{
    const int i = blockIdx.x * 256 + threadIdx.x;
    if (i < 2048) {
        const int p = i >> 10, rr = i & 1023;
        const int oc = rr >> 5, k = rr & 31;
        _Float16 val = (_Float16)0.f;
        if (k < 27) {
            float w = cw1[oc * 27 + k];
            _Float16 h = (_Float16)w;
            val = p ? (_Float16)(w - (float)h) : h;
        }
        w1s[p * 1024 + oc * 32 + k] = val;
    }
    if (i < 9216) {
        const int k = i % 9, r = i / 9;
        const int ic2 = r & 31, oc2 = r >> 5;
        {
            float w = cw2[(oc2 * 32 + ic2) * 9 + k];
            _Float16 h = (_Float16)w;
            w2s[(k * 2 + 0) * 1024 + oc2 * 32 + ic2] = h;
            w2s[(k * 2 + 1) * 1024 + oc2 * 32 + ic2] = (_Float16)(w - (float)h);
        }
        {
            float w = cw3[(oc2 * 32 + ic2) * 9 + k];
            _Float16 h = (_Float16)w;
            w3s[(k * 2 + 0) * 1024 + oc2 * 32 + ic2] = h;
            w3s[(k * 2 + 1) * 1024 + oc2 * 32 + ic2] = (_Float16)(w - (float)h);
        }
        {
            float w = cw4[(oc2 * 32 + ic2) * 9 + k];
            _Float16 h = (_Float16)w;
            w4s[(k * 2 + 0) * 1024 + oc2 * 32 + ic2] = h;
            w4s[(k * 2 + 1) * 1024 + oc2 * 32 + ic2] = (_Float16)(w - (float)h);
        }
    }
}

// ---------------- backbone: one block per image, 512 threads (8 waves) -----
// SPILL=true : LDS 32304 B (b1h 18432 + region2 13872); b1l in global scratch
//              (per-block 9216 f16), L2-resident. 4 blocks/CU.
// SPILL=false: round-8 layout, LDS 50736 B, 3 blocks/CU.
// region2 time-share: sxu [3][34][34] u32 -> b2h/b2l (4096 B ea) +
//                     b3h/b3l (2304 B ea at +8192) -> scr f32 partials.
// Swizzle: ic-group grp (8 ic) stored at slot (grp + (col>>1)) & 3.
template<bool SPILL>
__global__ __launch_bounds__(512, SPILL ? 8 : 6) void backbone_kernel(
    const float* __restrict__ x,
    const _Float16* __restrict__ w1s, const float* __restrict__ cb1,
    const _Float16* __restrict__ w2s, const float* __restrict__ cb2,
    const _Float16* __restrict__ w3s, const float* __restrict__ cb3,
    const _Float16* __restrict__ w4s, const float* __restrict__ cb4,
    _Float16* __restrict__ b1lg, float* __restrict__ t4)
{
    constexpr int SMEM_BYTES = SPILL ? 32304 : 50736;
    constexpr int R2_OFF     = SPILL ? 18432 : 36864;
    __shared__ __align__(16) unsigned char smem[SMEM_BYTES];
    _Float16* b1h = (_Float16*)smem;                    // 18432 B
    unsigned char* region2 = smem + R2_OFF;             // 13872 B
    unsigned* sxu = (unsigned*)region2;                 // 3468 u32
    _Float16* b2h = (_Float16*)region2;                 // 2048 el
    _Float16* b2l = (_Float16*)(region2 + 4096);        // 2048 el
    _Float16* b3h = (_Float16*)(region2 + 8192);        // 1152 el
    _Float16* b3l = (_Float16*)(region2 + 10496);       // 1152 el
    float*    scr = (float*)region2;                    // 2048 f32

    const int t = threadIdx.x;
    const int b = blockIdx.x;

    _Float16* b1l;
    if constexpr (SPILL) b1l = b1lg + (size_t)b * 9216;
    else                 b1l = (_Float16*)(smem + 18432);

    const int lane = t & 63;
    const int w  = __builtin_amdgcn_readfirstlane(t >> 6);  // wave id 0..7
    const int wr = w >> 1;                                   // row/px group 0..3
    const int mh = w & 1;                                    // oc half (M-split)
    const int xl = lane & 15;                                // MFMA col lane
    const int g  = lane >> 4;                                // MFMA k-group
    const int aoff = xl * 32 + g * 8;                        // A-frag offset

    // ---- init (halo zero) + image load, ONE barrier ----
    for (int i = t; i < 396; i += 512) {
        const int p = i / 132, r = i - p * 132;
        int row, col;
        if (r < 34)       { row = 0;       col = r; }
        else if (r < 68)  { row = 33;      col = r - 34; }
        else if (r < 100) { row = r - 67;  col = 0; }
        else              { row = r - 99;  col = 33; }
        sxu[p * 1156 + row * 34 + col] = 0;
    }
    // b1 halo columns (c = 0, 17) for both planes
    if constexpr (SPILL) {
        if (t < 512) {
            const int j = t & 15, cs = (t >> 4) & 1, r = (t >> 5) & 15;
            const int e = (r * 18 + (cs ? 17 : 0)) * 16 + j;
            ((unsigned*)b1h)[e] = 0;
            ((unsigned*)b1l)[e] = 0;            // global halo zero
        }
    } else {
        for (int i = t; i < 1024; i += 512) {
            const int j = i & 15, cs = (i >> 4) & 1, r = (i >> 5) & 15, P = i >> 9;
            ((unsigned*)(smem + P * 18432))[(r * 18 + (cs ? 17 : 0)) * 16 + j] = 0;
        }
    }
    // image load: split h/l, pack as u32 (h lo16 | l hi16) via v_perm
    {
        const float* xb = x + (size_t)b * 3072;
        for (int i = t; i < 3072; i += 512) {
            const int ic = i >> 10, r = i & 1023;
            const float v = xb[i];
            const _Float16 h = (_Float16)v;
            const _Float16 l = (_Float16)(v - (float)h);
            const unsigned hu = (unsigned)__builtin_bit_cast(unsigned short, h);
            const unsigned lu = (unsigned)__builtin_bit_cast(unsigned short, l);
            sxu[ic * 1156 + ((r >> 5) + 1) * 34 + (r & 31) + 1] =
                __builtin_amdgcn_perm(lu, hu, 0x05040100u);
        }
    }
    __syncthreads();

    // ---- conv1 (MFMA, K=27 pad 32): rows split, each wave 2 pooled rows ----
    {
        const f16x8 ah0 = *(const f16x8*)(w1s + xl * 32 + g * 8);
        const f16x8 ah1 = *(const f16x8*)(w1s + (16 + xl) * 32 + g * 8);
        const f16x8 al0 = *(const f16x8*)(w1s + 1024 + xl * 32 + g * 8);
        const f16x8 al1 = *(const f16x8*)(w1s + 1024 + (16 + xl) * 32 + g * 8);
        const f32x4 cbias0 = *(const f32x4*)(cb1 + g * 4);
        const f32x4 cbias1 = *(const f32x4*)(cb1 + 16 + g * 4);

        int off_j[8];
        #pragma unroll
        for (int j = 0; j < 8; ++j) {
            int k = g * 8 + j; if (k > 26) k = 26;
            const int ic = k / 9, t9 = k - ic * 9;
            const int dy = t9 / 3, dx = t9 - dy * 3;
            off_j[j] = ic * 1156 + dy * 34 + dx;
        }

        #pragma unroll
        for (int q = 0; q < 2; ++q) {
            const int rp = w * 2 + q;           // pooled row 0..15
            const int y0 = 2 * rp;
            #pragma unroll
            for (int xt = 0; xt < 2; ++xt) {
                const int xpix = xt * 16 + xl;
                f32x4 acc[2][2];
                #pragma unroll
                for (int yy = 0; yy < 2; ++yy)
                    #pragma unroll
                    for (int m = 0; m < 2; ++m)
                        #pragma unroll
                        for (int r = 0; r < 4; ++r) acc[yy][m][r] = 0.f;
                #pragma unroll
                for (int yy = 0; yy < 2; ++yy) {
                    const int base = (y0 + yy) * 34 + xpix;
                    unsigned e[8];
                    #pragma unroll
                    for (int j = 0; j < 8; ++j) e[j] = sxu[off_j[j] + base];
                    U16x8 Bh, Bl;
                    #pragma unroll
                    for (int p = 0; p < 4; ++p) {
                        const unsigned e0 = e[2 * p], e1 = e[2 * p + 1];
                        Bh.u[p] = __builtin_amdgcn_perm(e1, e0, 0x05040100u);
                        Bl.u[p] = __builtin_amdgcn_perm(e1, e0, 0x07060302u);
                    }
                    acc[yy][0] = __builtin_amdgcn_mfma_f32_16x16x32_f16(ah0, Bh.v, acc[yy][0], 0, 0, 0);
                    acc[yy][0] = __builtin_amdgcn_mfma_f32_16x16x32_f16(ah0, Bl.v, acc[yy][0], 0, 0, 0);
                    acc[yy][0] = __builtin_amdgcn_mfma_f32_16x16x32_f16(al0, Bh.v, acc[yy][0], 0, 0, 0);
                    acc[yy][1] = __builtin_amdgcn_mfma_f32_16x16x32_f16(ah1, Bh.v, acc[yy][1], 0, 0, 0);
                    acc[yy][1] = __builtin_amdgcn_mfma_f32_16x16x32_f16(ah1, Bl.v, acc[yy][1], 0, 0, 0);
                    acc[yy][1] = __builtin_amdgcn_mfma_f32_16x16x32_f16(al1, Bh.v, acc[yy][1], 0, 0, 0);
                }
                #pragma unroll
                for (int m = 0; m < 2; ++m) {
                    f32x4 vv;
                    #pragma unroll
                    for (int r = 0; r < 4; ++r) {
                        float v = fmaxf(acc[0][m][r], acc[1][m][r]);
                        v = fmaxf(v, __shfl_xor(v, 1));
                        vv[r] = fmaxf(v + (m ? cbias1[r] : cbias0[r]), 0.f);
                    }
                    if ((xl & 1) == 0) {
                        const int c = xt * 8 + (xl >> 1) + 1;     // col 1..16
                        const int grp = m * 2 + (g >> 1);
                        const int so = (grp + (c >> 1)) & 3;
                        const int e = (rp * 18 + c) * 32 + so * 8 + (g & 1) * 4;
                        f16x4 h4, l4;
                        #pragma unroll
                        for (int r = 0; r < 4; ++r) {
                            const _Float16 h = (_Float16)vv[r];
                            h4[r] = h;
                            l4[r] = (_Float16)(vv[r] - (float)h);
                        }
                        *(f16x4*)(b1h + e) = h4;
                        *(f16x4*)(b1l + e) = l4;      // LDS or global per variant
                    }
                }
            }
        }
    }
    __syncthreads();   // also drains conv1's global b1l stores (vmcnt 0)

    // ---- conv2 (MFMA): rows split, each wave 2 pre-pool rows -> b2 ----
    {
        // zero b3 region (aliases dead sx tail); used two phases later
        for (int i = t; i < 1152; i += 512) ((unsigned*)(region2 + 8192))[i] = 0;

        f32x4 acc[2][2];    // [j][m]
        #pragma unroll
        for (int j = 0; j < 2; ++j)
            #pragma unroll
            for (int m = 0; m < 2; ++m)
                #pragma unroll
                for (int r = 0; r < 4; ++r) acc[j][m][r] = 0.f;

        #pragma unroll
        for (int dy = 0; dy < 3; ++dy) {
            #pragma unroll
            for (int dx = 0; dx < 3; ++dx) {
                const _Float16* wb = w2s + (dy * 3 + dx) * 2048;
                const f16x8 ah0 = *(const f16x8*)(wb + aoff);
                const f16x8 ah1 = *(const f16x8*)(wb + 512 + aoff);
                const f16x8 al0 = *(const f16x8*)(wb + 1024 + aoff);
                const f16x8 al1 = *(const f16x8*)(wb + 1536 + aoff);

                const int cxs = xl + dx;                  // storage col 0..17
                const int so = (g + (cxs >> 1)) & 3;
                #pragma unroll
                for (int j = 0; j < 2; ++j) {
                    const int sy = 2 * w + j + dy - 1;    // wave-uniform
                    if ((unsigned)sy < 16u) {
                        const int e = (sy * 18 + cxs) * 32 + so * 8;
                        const f16x8 bh = *(const f16x8*)(b1h + e);
                        const f16x8 bl = *(const f16x8*)(b1l + e);
                        acc[j][0] = __builtin_amdgcn_mfma_f32_16x16x32_f16(ah0, bh, acc[j][0], 0, 0, 0);
                        acc[j][0] = __builtin_amdgcn_mfma_f32_16x16x32_f16(ah0, bl, acc[j][0], 0, 0, 0);
                        acc[j][0] = __builtin_amdgcn_mfma_f32_16x16x32_f16(al0, bh, acc[j][0], 0, 0, 0);
                        acc[j][1] = __builtin_amdgcn_mfma_f32_16x16x32_f16(ah1, bh, acc[j][1], 0, 0, 0);
                        acc[j][1] = __builtin_amdgcn_mfma_f32_16x16x32_f16(ah1, bl, acc[j][1], 0, 0, 0);
                        acc[j][1] = __builtin_amdgcn_mfma_f32_16x16x32_f16(al1, bh, acc[j][1], 0, 0, 0);
                    }
                }
            }
        }

        // epilogue: pool 2x2 + bias + relu, split fp16 h/l -> b2 [64px][32ic]
        const f32x4 bias0 = *(const f32x4*)(cb2 + g * 4);
        const f32x4 bias1 = *(const f32x4*)(cb2 + 16 + g * 4);
        #pragma unroll
        for (int m = 0; m < 2; ++m) {
            f32x4 vv;
            #pragma unroll
            for (int r = 0; r < 4; ++r) {
                float v = fmaxf(acc[0][m][r], acc[1][m][r]);
                v = fmaxf(v, __shfl_xor(v, 1));
                vv[r] = fmaxf(v + (m ? bias1[r] : bias0[r]), 0.f);
            }
            if ((lane & 1) == 0) {
                const int pp = w * 8 + (xl >> 1);         // pooled px 0..63
                const int slot = m * 2 + (g >> 1);
                const int so2 = (slot + (pp >> 1)) & 3;
                const int e = pp * 32 + so2 * 8 + (g & 1) * 4;
                f16x4 h4, l4;
                #pragma unroll
                for (int r = 0; r < 4; ++r) {
                    const _Float16 h = (_Float16)vv[r];
                    h4[r] = h;
                    l4[r] = (_Float16)(vv[r] - (float)h);
                }
                *(f16x4*)(b2h + e) = h4;
                *(f16x4*)(b2l + e) = l4;
            }
        }
    }
    __syncthreads();

    // ---- conv3 (MFMA, oc-split): wave pair (wr,mh) -> b3 padded ----
    {
        const int p = wr * 16 + xl;          // pre-pool pixel 0..63
        const int py3 = p >> 3, px3 = p & 7;
        f32x4 acc;
        #pragma unroll
        for (int r = 0; r < 4; ++r) acc[r] = 0.f;

        #pragma unroll
        for (int dy = 0; dy < 3; ++dy) {
            #pragma unroll
            for (int dx = 0; dx < 3; ++dx) {
                const _Float16* wb = w3s + (dy * 3 + dx) * 2048 + mh * 512;
                const f16x8 ah = *(const f16x8*)(wb + aoff);
                const f16x8 al = *(const f16x8*)(wb + 1024 + aoff);

                const int syL = py3 + dy - 1, sxL = px3 + dx - 1;
                const bool ok = ((unsigned)syL < 8u) && ((unsigned)sxL < 8u);
                const int cy = syL < 0 ? 0 : (syL > 7 ? 7 : syL);
                const int cx = sxL < 0 ? 0 : (sxL > 7 ? 7 : sxL);
                const int cp = cy * 8 + cx;
                const int so = (g + (cp >> 1)) & 3;
                const int e = cp * 32 + so * 8;
                f16x8 bh = *(const f16x8*)(b2h + e);
                f16x8 bl = *(const f16x8*)(b2l + e);
                if (!ok) { bh = f16x8_zero(); bl = f16x8_zero(); }
                acc = __builtin_amdgcn_mfma_f32_16x16x32_f16(ah, bh, acc, 0, 0, 0);
                acc = __builtin_amdgcn_mfma_f32_16x16x32_f16(ah, bl, acc, 0, 0, 0);
                acc = __builtin_amdgcn_mfma_f32_16x16x32_f16(al, bh, acc, 0, 0, 0);
            }
        }

        const f32x4 bias = *(const f32x4*)(cb3 + mh * 16 + g * 4);
        f32x4 vv;
        #pragma unroll
        for (int r = 0; r < 4; ++r) {
            float v = acc[r];
            v = fmaxf(v, __shfl_xor(v, 1));
            v = fmaxf(v, __shfl_xor(v, 8));
            vv[r] = fmaxf(v + bias[r], 0.f);
        }
        if ((lane & 9) == 0) {     // x even, y even
            const int yr = wr;                 // pooled row 0..3
            const int xr = (xl & 7) >> 1;      // pooled col 0..3
            const int pp3 = (yr + 1) * 6 + (xr + 1);
            const int grp = mh * 2 + (g >> 1);
            const int so = (grp + (pp3 >> 1)) & 3;
            const int e = pp3 * 32 + so * 8 + (g & 1) * 4;
            f16x4 h4, l4;
            #pragma unroll
            for (int r = 0; r < 4; ++r) {
                const _Float16 h = (_Float16)vv[r];
                h4[r] = h;
                l4[r] = (_Float16)(vv[r] - (float)h);
            }
            *(f16x4*)(b3h + e) = h4;
            *(f16x4*)(b3l + e) = l4;
        }
    }
    __syncthreads();

    // ---- conv4 (MFMA, tap+oc split): taps {wr,wr+4,wr+8}, half mh ----
    {
        f32x4 a4;
        #pragma unroll
        for (int r = 0; r < 4; ++r) a4[r] = 0.f;

        for (int t9 = wr; t9 < 9; t9 += 4) {
            const _Float16* wb = w4s + t9 * 2048 + mh * 512;
            const f16x8 ah = *(const f16x8*)(wb + aoff);
            const f16x8 al = *(const f16x8*)(wb + 1024 + aoff);
            const int dy = t9 / 3, dx = t9 - dy * 3;
            const int pp3 = ((xl >> 2) + dy) * 6 + (xl & 3) + dx;
            const int so = (g + (pp3 >> 1)) & 3;
            const int e = pp3 * 32 + so * 8;
            const f16x8 bh = *(const f16x8*)(b3h + e);
            const f16x8 bl = *(const f16x8*)(b3l + e);
            a4 = __builtin_amdgcn_mfma_f32_16x16x32_f16(ah, bh, a4, 0, 0, 0);
            a4 = __builtin_amdgcn_mfma_f32_16x16x32_f16(ah, bl, a4, 0, 0, 0);
            a4 = __builtin_amdgcn_mfma_f32_16x16x32_f16(al, bh, a4, 0, 0, 0);
        }
        *(f32x4*)(scr + (w * 64 + lane) * 4) = a4;
        __syncthreads();

        if (w < 2) {     // wave 0 reduces mh=0, wave 1 reduces mh=1
            f32x4 r0;
            #pragma unroll
            for (int r = 0; r < 4; ++r) r0[r] = 0.f;
            #pragma unroll
            for (int k = 0; k < 4; ++k) {
                const f32x4 p0 = *(const f32x4*)(scr + ((k * 2 + w) * 64 + lane) * 4);
                #pragma unroll
                for (int r = 0; r < 4; ++r) r0[r] += p0[r];
            }
            const f32x4 bias = *(const f32x4*)(cb4 + w * 16 + g * 4);
            const int y = xl >> 2, xx = xl & 3;
            f32x4 vv;
            #pragma unroll
            for (int r = 0; r < 4; ++r) {
                float v = r0[r];
                v = fmaxf(v, __shfl_xor(v, 1));
                v = fmaxf(v, __shfl_xor(v, 4));
                vv[r] = fmaxf(v + bias[r], 0.f);
            }
            if ((xl & 5) == 0) {       // x even, y even
                const int oc0 = w * 16 + g * 4;
                #pragma unroll
                for (int r = 0; r < 4; ++r)
                    t4[(size_t)b * 128 + (oc0 + r) * 4 + (y >> 1) * 2 + (xx >> 1)] = vv[r];
            }
        }
    }
}

// ---------------- BN batch stats, stage A: 256 blocks of partials ----------
__global__ __launch_bounds__(256) void bnstatsA_kernel(
    const float* __restrict__ t4, double* __restrict__ part)
{
    __shared__ double ssum[256];
    __shared__ double ssq[256];
    const int c = blockIdx.x >> 3, s = blockIdx.x & 7, t = threadIdx.x;
    const float* base = t4 + (size_t)s * 512 * 128 + c * 4;
    double sm = 0.0, q = 0.0;
    for (int j = t; j < 2048; j += 256) {
        const float v = base[(size_t)(j >> 2) * 128 + (j & 3)];
        sm += (double)v;
        q += (double)v * (double)v;
    }
    ssum[t] = sm; ssq[t] = q;
    __syncthreads();
    for (int w = 128; w > 0; w >>= 1) {
        if (t < w) { ssum[t] += ssum[t + w]; ssq[t] += ssq[t + w]; }
        __syncthreads();
    }
    if (t == 0) {
        part[(c * 8 + s) * 2]     = ssum[0];
        part[(c * 8 + s) * 2 + 1] = ssq[0];
    }
}

// ---------------- BN batch stats, stage B: reduce 8 partials/channel -------
__global__ __launch_bounds__(256) void bnstatsB_kernel(
    const double* __restrict__ part, float* __restrict__ mus, float* __restrict__ rss)
{
    const int t = threadIdx.x;               // c = t>>3, s = t&7 (8-lane groups)
    double sm = part[t * 2], q = part[t * 2 + 1];
    #pragma unroll
    for (int d = 1; d < 8; d <<= 1) {
        sm += __shfl_xor(sm, d);
        q += __shfl_xor(q, d);
    }
    if ((t & 7) == 0) {
        const double mu = sm / 16384.0;
        const double var = q / 16384.0 - mu * mu;
        mus[t >> 3] = (float)mu;
        rss[t >> 3] = (float)(1.0 / sqrt(var + 1e-5));
    }
}

// ---------------- routing: 4 samples/block, wave-synchronous ---------------
__device__ __forceinline__ int wave_argmax16(double v, int idx) {
    #pragma unroll
    for (int d = 8; d >= 1; d >>= 1) {
        const double ov = __shfl_xor(v, d);
        const int oi = __shfl_xor(idx, d);
        if (ov > v || (ov == v && oi < idx)) { v = ov; idx = oi; }
    }
    return __shfl(idx, 0);
}

__global__ __launch_bounds__(256) void routing_kernel(
    const float* __restrict__ t4, const float* __restrict__ mus,
    const float* __restrict__ rss,
    const float* __restrict__ bng, const float* __restrict__ bnb,
    const float* __restrict__ wpt, const float* __restrict__ wd1,
    const float* __restrict__ wd2, const float* __restrict__ wd3,
    const float* __restrict__ s1w, const float* __restrict__ s1b,
    const float* __restrict__ s2w, const float* __restrict__ s2b,
    const float* __restrict__ s3w, const float* __restrict__ s3b,
    float* __restrict__ out)
{
    __shared__ float fs[4][128];
    __shared__ float h1s[4][48];
    __shared__ float h2s[4][48];
    const int t = threadIdx.x & 63;
    const int w = threadIdx.x >> 6;
    const int b = blockIdx.x * 4 + w;
    float* fw  = fs[w];
    float* h1w = h1s[w];
    float* h2w = h2s[w];

    for (int i = t; i < 128; i += 64) {
        const int c = i >> 2;
        const float v = t4[(size_t)b * 128 + i];
        fw[i] = (v - mus[c]) * rss[c] * bng[c] + bnb[c];
    }
    __builtin_amdgcn_wave_barrier();

    // task assignment: argmax over 10 agents (fp64, 4-wide unroll)
    double a = -INFINITY;
    if (t < 10) {
        double s0 = 0, s1 = 0, s2 = 0, s3 = 0;
        for (int k = 0; k < 128; k += 4) {
            s0 = fma((double)fw[k],     (double)wpt[k * 10 + t],       s0);
            s1 = fma((double)fw[k + 1], (double)wpt[(k + 1) * 10 + t], s1);
            s2 = fma((double)fw[k + 2], (double)wpt[(k + 2) * 10 + t], s2);
            s3 = fma((double)fw[k + 3], (double)wpt[(k + 3) * 10 + t], s3);
        }
        a = (s0 + s1) + (s2 + s3);
    }
    const int agent = wave_argmax16(a, t & 15);

    // decision 1
    a = -INFINITY;
    if (t < 16) {
        const float* wd = wd1 + (size_t)agent * 2048 + t;
        double s0 = 0, s1 = 0, s2 = 0, s3 = 0;
        for (int k = 0; k < 128; k += 4) {
            s0 = fma((double)fw[k],     (double)wd[k * 16],       s0);
            s1 = fma((double)fw[k + 1], (double)wd[(k + 1) * 16], s1);
            s2 = fma((double)fw[k + 2], (double)wd[(k + 2) * 16], s2);
            s3 = fma((double)fw[k + 3], (double)wd[(k + 3) * 16], s3);
        }
        a = (s0 + s1) + (s2 + s3);
    }
    const int a1 = wave_argmax16(a, t & 15);

    // expert layer 1: 128 -> 48, relu
    if (t < 48) {
        const float* wd = s1w + (size_t)a1 * 6144 + t;
        float c0 = s1b[a1 * 48 + t], c1 = 0.f, c2 = 0.f, c3 = 0.f;
        for (int k = 0; k < 128; k += 4) {
            c0 = fmaf(fw[k],     wd[k * 48],       c0);
            c1 = fmaf(fw[k + 1], wd[(k + 1) * 48], c1);
            c2 = fmaf(fw[k + 2], wd[(k + 2) * 48], c2);
            c3 = fmaf(fw[k + 3], wd[(k + 3) * 48], c3);
        }
        h1w[t] = fmaxf((c0 + c1) + (c2 + c3), 0.f);
    }
    __builtin_amdgcn_wave_barrier();

    // decision 2
    a = -INFINITY;
    if (t < 16) {
        const float* wd = wd2 + (size_t)agent * 768 + t;
        double s0 = 0, s1 = 0, s2 = 0, s3 = 0;
        for (int k = 0; k < 48; k += 4) {
            s0 = fma((double)h1w[k],     (double)wd[k * 16],       s0);
            s1 = fma((double)h1w[k + 1], (double)wd[(k + 1) * 16], s1);
            s2 = fma((double)h1w[k + 2], (double)wd[(k + 2) * 16], s2);
            s3 = fma((double)h1w[k + 3], (double)wd[(k + 3) * 16], s3);
        }
        a = (s0 + s1) + (s2 + s3);
    }
    const int a2 = wave_argmax16(a, t & 15);

    // expert layer 2: 48 -> 48, relu
    if (t < 48) {
        const float* wd = s2w + (size_t)a2 * 2304 + t;
        float c0 = s2b[a2 * 48 + t], c1 = 0.f, c2 = 0.f, c3 = 0.f;
        for (int k = 0; k < 48; k += 4) {
            c0 = fmaf(h1w[k],     wd[k * 48],       c0);
            c1 = fmaf(h1w[k + 1], wd[(k + 1) * 48], c1);
            c2 = fmaf(h1w[k + 2], wd[(k + 2) * 48], c2);
            c3 = fmaf(h1w[k + 3], wd[(k + 3) * 48], c3);
        }
        h2w[t] = fmaxf((c0 + c1) + (c2 + c3), 0.f);
    }
    __builtin_amdgcn_wave_barrier();

    // decision 3
    a = -INFINITY;
    if (t < 16) {
        const float* wd = wd3 + (size_t)agent * 768 + t;
        double s0 = 0, s1 = 0, s2 = 0, s3 = 0;
        for (int k = 0; k < 48; k += 4) {
            s0 = fma((double)h2w[k],     (double)wd[k * 16],       s0);
            s1 = fma((double)h2w[k + 1], (double)wd[(k + 1) * 16], s1);
            s2 = fma((double)h2w[k + 2], (double)wd[(k + 2) * 16], s2);
            s3 = fma((double)h2w[k + 3], (double)wd[(k + 3) * 16], s3);
        }
        a = (s0 + s1) + (s2 + s3);
    }
    const int a3 = wave_argmax16(a, t & 15);

    // expert layer 3: 48 -> 10, no relu
    if (t < 10) {
        const float* wd = s3w + (size_t)a3 * 480 + t;
        float c0 = s3b[a3 * 10 + t], c1 = 0.f, c2 = 0.f, c3 = 0.f;
        for (int k = 0; k < 48; k += 4) {
            c0 = fmaf(h2w[k],     wd[k * 10],       c0);
            c1 = fmaf(h2w[k + 1], wd[(k + 1) * 10], c1);
            c2 = fmaf(h2w[k + 2], wd[(k + 2) * 10], c2);
            c3 = fmaf(h2w[k + 3], wd[(k + 3) * 10], c3);
        }
        out[(size_t)b * 10 + t] = (c0 + c1) + (c2 + c3);
    }
}

// ---------------------------------------------------------------------------
extern "C" void kernel_launch(void* const* d_in, const int* in_sizes, int n_in,
                              void* d_out, int out_size, void* d_ws, size_t ws_size,
                              hipStream_t stream)
{
    (void)in_sizes; (void)n_in; (void)out_size;

    const float* x   = (const float*)d_in[0];
    const float* cw1 = (const float*)d_in[2];
    const float* cb1 = (const float*)d_in[3];
    const float* cw2 = (const float*)d_in[4];
    const float* cb2 = (const float*)d_in[5];
    const float* cw3 = (const float*)d_in[6];
    const float* cb3 = (const float*)d_in[7];
    const float* cw4 = (const float*)d_in[8];
    const float* cb4 = (const float*)d_in[9];
    const float* bng = (const float*)d_in[10];
    const float* bnb = (const float*)d_in[11];
    const float* wpt = (const float*)d_in[12];
    const float* wd1 = (const float*)d_in[13];
    const float* wd2 = (const float*)d_in[14];
    const float* wd3 = (const float*)d_in[15];
    const float* s1w = (const float*)d_in[16];
    const float* s1b = (const float*)d_in[17];
    const float* s2w = (const float*)d_in[18];
    const float* s2b = (const float*)d_in[19];
    const float* s3w = (const float*)d_in[20];
    const float* s3b = (const float*)d_in[21];
    float* out = (float*)d_out;

    float* t4  = (float*)d_ws;                       // [4096][128]
    float* mus = t4 + (size_t)IMG_B * 128;           // 32
    float* rss = mus + 32;                           // 32
    _Float16* w1s = (_Float16*)(rss + 32);           // 2048 f16
    _Float16* w2s = w1s + 2048;                      // 18432 f16
    _Float16* w3s = w2s + 18432;                     // 18432 f16
    _Float16* w4s = w3s + 18432;                     // 18432 f16
    double* part = (double*)(w4s + 18432);           // 512 doubles
    _Float16* b1lg = (_Float16*)(part + 512);        // [4096][9216] f16 (spill)

    const size_t need = (size_t)((char*)(b1lg + (size_t)IMG_B * 9216) - (char*)d_ws);
    const bool spill = (ws_size >= need);

    hipLaunchKernelGGL(twt_kernel, dim3(36), dim3(256), 0, stream,
                       cw1, cw2, cw3, cw4, w1s, w2s, w3s, w4s);
    if (spill) {
        hipLaunchKernelGGL((backbone_kernel<true>), dim3(IMG_B), dim3(512), 0, stream,
                           x, w1s, cb1, w2s, cb2, w3s, cb3, w4s, cb4, b1lg, t4);
    } else {
        hipLaunchKernelGGL((backbone_kernel<false>), dim3(IMG_B), dim3(512), 0, stream,
                           x, w1s, cb1, w2s, cb2, w3s, cb3, w4s, cb4, b1lg, t4);
    }
    hipLaunchKernelGGL(bnstatsA_kernel, dim3(256), dim3(256), 0, stream, t4, part);
    hipLaunchKernelGGL(bnstatsB_kernel, dim3(1), dim3(256), 0, stream, part, mus, rss);
    hipLaunchKernelGGL(routing_kernel, dim3(IMG_B / 4), dim3(256), 0, stream,
                       t4, mus, rss, bng, bnb, wpt, wd1, wd2, wd3,
                       s1w, s1b, s2w, s2b, s3w, s3b, out);
}

// Round 10
// 173.342 us; speedup vs baseline: 1.4898x; 1.4898x over previous
//
#include <hip/hip_runtime.h>
#include <math.h>

// ---------------------------------------------------------------------------
// RoutedAllFC round 10: revert to round-8 LDS-resident backbone (known-good
// 175us, absmax 0.0039) — round 9's global-scratch spill thrashed L2->HBM
// (FETCH 26MB->265MB). Additions over r8:
//  - s_setprio(1) around MFMA compute regions (T5: cross-block phase skew
//    gives wave role diversity on each CU)
//  - float2 image loads (pair always within one row)
// ---------------------------------------------------------------------------

#define IMG_B 4096

typedef _Float16 f16x8 __attribute__((ext_vector_type(8)));
typedef _Float16 f16x4 __attribute__((ext_vector_type(4)));
typedef float    f32x4 __attribute__((ext_vector_type(4)));

union U16x8 { unsigned u[4]; f16x8 v; };

__device__ inline f16x8 f16x8_zero() {
    f16x8 z;
    #pragma unroll
    for (int i = 0; i < 8; ++i) z[i] = (_Float16)0.f;
    return z;
}

// ---- weight prep: fp16 h/l split for all convs --------------------------
// w1s: [part][oc(32)][k(32)]  k = ic*9 + dy*3 + dx, k>=27 -> 0
// w2s/w3s/w4s: [tap][part][oc(32)][ic(32)]
__global__ __launch_bounds__(256) void twt_kernel(
    const float* __restrict__ cw1, const float* __restrict__ cw2,
    const float* __restrict__ cw3, const float* __restrict__ cw4,
    _Float16* __restrict__ w1s, _Float16* __restrict__ w2s,
    _Float16* __restrict__ w3s, _Float16* __restrict__ w4s)
{
    const int i = blockIdx.x * 256 + threadIdx.x;
    if (i < 2048) {
        const int p = i >> 10, rr = i & 1023;
        const int oc = rr >> 5, k = rr & 31;
        _Float16 val = (_Float16)0.f;
        if (k < 27) {
            float w = cw1[oc * 27 + k];
            _Float16 h = (_Float16)w;
            val = p ? (_Float16)(w - (float)h) : h;
        }
        w1s[p * 1024 + oc * 32 + k] = val;
    }
    if (i < 9216) {
        const int k = i % 9, r = i / 9;
        const int ic2 = r & 31, oc2 = r >> 5;
        {
            float w = cw2[(oc2 * 32 + ic2) * 9 + k];
            _Float16 h = (_Float16)w;
            w2s[(k * 2 + 0) * 1024 + oc2 * 32 + ic2] = h;
            w2s[(k * 2 + 1) * 1024 + oc2 * 32 + ic2] = (_Float16)(w - (float)h);
        }
        {
            float w = cw3[(oc2 * 32 + ic2) * 9 + k];
            _Float16 h = (_Float16)w;
            w3s[(k * 2 + 0) * 1024 + oc2 * 32 + ic2] = h;
            w3s[(k * 2 + 1) * 1024 + oc2 * 32 + ic2] = (_Float16)(w - (float)h);
        }
        {
            float w = cw4[(oc2 * 32 + ic2) * 9 + k];
            _Float16 h = (_Float16)w;
            w4s[(k * 2 + 0) * 1024 + oc2 * 32 + ic2] = h;
            w4s[(k * 2 + 1) * 1024 + oc2 * 32 + ic2] = (_Float16)(w - (float)h);
        }
    }
}

// ---------------- backbone: one block per image, 512 threads (8 waves) -----
// LDS (50736 B):
//   b1h/b1l : [16 rows][18 cols][32 ic] fp16, col-padded, swizzled (18432 B ea)
//   region2 (13872 B), time-shared:
//     conv1 : sxu [3][34][34] u32 (h lo16, l hi16)
//     conv2+: b2h/b2l [64 px][32 ic] (4096 B ea), b3h/b3l [36 px][32 ic]
//             padded (2304 B ea at +8192)
//     conv4 : scr [8 waves][64 lanes][4] f32 partials (8192 B at +0)
// Swizzle: ic-group grp (8 ic) stored at slot (grp + (col>>1)) & 3.
// Barriers: 5.
__global__ __launch_bounds__(512, 6) void backbone_kernel(
    const float* __restrict__ x,
    const _Float16* __restrict__ w1s, const float* __restrict__ cb1,
    const _Float16* __restrict__ w2s, const float* __restrict__ cb2,
    const _Float16* __restrict__ w3s, const float* __restrict__ cb3,
    const _Float16* __restrict__ w4s, const float* __restrict__ cb4,
    float* __restrict__ t4)
{
    __shared__ __align__(16) unsigned char smem[50736];
    _Float16* b1h = (_Float16*)smem;                    // 18432 B
    _Float16* b1l = (_Float16*)(smem + 18432);          // 18432 B
    unsigned char* region2 = smem + 36864;              // 13872 B
    unsigned* sxu = (unsigned*)region2;                 // 3468 u32
    _Float16* b2h = (_Float16*)region2;                 // 2048 el
    _Float16* b2l = (_Float16*)(region2 + 4096);        // 2048 el
    _Float16* b3h = (_Float16*)(region2 + 8192);        // 1152 el
    _Float16* b3l = (_Float16*)(region2 + 10496);       // 1152 el
    float*    scr = (float*)region2;                    // 2048 f32

    const int t = threadIdx.x;
    const int b = blockIdx.x;
    const int lane = t & 63;
    const int w  = __builtin_amdgcn_readfirstlane(t >> 6);  // wave id 0..7
    const int wr = w >> 1;                                   // row/px group 0..3
    const int mh = w & 1;                                    // oc half (M-split)
    const int xl = lane & 15;                                // MFMA col lane
    const int g  = lane >> 4;                                // MFMA k-group
    const int aoff = xl * 32 + g * 8;                        // A-frag offset

    // ---- init (halo zero) + image load, ONE barrier ----
    for (int i = t; i < 396; i += 512) {
        const int p = i / 132, r = i - p * 132;
        int row, col;
        if (r < 34)       { row = 0;       col = r; }
        else if (r < 68)  { row = 33;      col = r - 34; }
        else if (r < 100) { row = r - 67;  col = 0; }
        else              { row = r - 99;  col = 33; }
        sxu[p * 1156 + row * 34 + col] = 0;
    }
    // b1 halo columns (c = 0, 17) for both planes
    for (int i = t; i < 1024; i += 512) {
        const int j = i & 15, cs = (i >> 4) & 1, r = (i >> 5) & 15, P = i >> 9;
        ((unsigned*)(smem + P * 18432))[(r * 18 + (cs ? 17 : 0)) * 16 + j] = 0;
    }
    // image load as float2 (pair index even -> same row, consecutive cols):
    // split h/l, pack as u32 (h lo16 | l hi16) via v_perm
    {
        const float2* xb2 = (const float2*)(x + (size_t)b * 3072);
        for (int i = t; i < 1536; i += 512) {
            const float2 v2 = xb2[i];
            const int e0i = 2 * i;
            const int ic = e0i >> 10, r = e0i & 1023;
            const int o = ic * 1156 + ((r >> 5) + 1) * 34 + (r & 31) + 1;
            {
                const _Float16 h = (_Float16)v2.x;
                const _Float16 l = (_Float16)(v2.x - (float)h);
                const unsigned hu = (unsigned)__builtin_bit_cast(unsigned short, h);
                const unsigned lu = (unsigned)__builtin_bit_cast(unsigned short, l);
                sxu[o] = __builtin_amdgcn_perm(lu, hu, 0x05040100u);
            }
            {
                const _Float16 h = (_Float16)v2.y;
                const _Float16 l = (_Float16)(v2.y - (float)h);
                const unsigned hu = (unsigned)__builtin_bit_cast(unsigned short, h);
                const unsigned lu = (unsigned)__builtin_bit_cast(unsigned short, l);
                sxu[o + 1] = __builtin_amdgcn_perm(lu, hu, 0x05040100u);
            }
        }
    }
    __syncthreads();

    // ---- conv1 (MFMA, K=27 pad 32): rows split, each wave 2 pooled rows ----
    {
        const f16x8 ah0 = *(const f16x8*)(w1s + xl * 32 + g * 8);
        const f16x8 ah1 = *(const f16x8*)(w1s + (16 + xl) * 32 + g * 8);
        const f16x8 al0 = *(const f16x8*)(w1s + 1024 + xl * 32 + g * 8);
        const f16x8 al1 = *(const f16x8*)(w1s + 1024 + (16 + xl) * 32 + g * 8);
        const f32x4 cbias0 = *(const f32x4*)(cb1 + g * 4);
        const f32x4 cbias1 = *(const f32x4*)(cb1 + 16 + g * 4);

        int off_j[8];
        #pragma unroll
        for (int j = 0; j < 8; ++j) {
            int k = g * 8 + j; if (k > 26) k = 26;
            const int ic = k / 9, t9 = k - ic * 9;
            const int dy = t9 / 3, dx = t9 - dy * 3;
            off_j[j] = ic * 1156 + dy * 34 + dx;
        }

        __builtin_amdgcn_s_setprio(1);
        #pragma unroll
        for (int q = 0; q < 2; ++q) {
            const int rp = w * 2 + q;           // pooled row 0..15
            const int y0 = 2 * rp;
            #pragma unroll
            for (int xt = 0; xt < 2; ++xt) {
                const int xpix = xt * 16 + xl;
                f32x4 acc[2][2];
                #pragma unroll
                for (int yy = 0; yy < 2; ++yy)
                    #pragma unroll
                    for (int m = 0; m < 2; ++m)
                        #pragma unroll
                        for (int r = 0; r < 4; ++r) acc[yy][m][r] = 0.f;
                #pragma unroll
                for (int yy = 0; yy < 2; ++yy) {
                    const int base = (y0 + yy) * 34 + xpix;
                    unsigned e[8];
                    #pragma unroll
                    for (int j = 0; j < 8; ++j) e[j] = sxu[off_j[j] + base];
                    U16x8 Bh, Bl;
                    #pragma unroll
                    for (int p = 0; p < 4; ++p) {
                        const unsigned e0 = e[2 * p], e1 = e[2 * p + 1];
                        Bh.u[p] = __builtin_amdgcn_perm(e1, e0, 0x05040100u);
                        Bl.u[p] = __builtin_amdgcn_perm(e1, e0, 0x07060302u);
                    }
                    acc[yy][0] = __builtin_amdgcn_mfma_f32_16x16x32_f16(ah0, Bh.v, acc[yy][0], 0, 0, 0);
                    acc[yy][0] = __builtin_amdgcn_mfma_f32_16x16x32_f16(ah0, Bl.v, acc[yy][0], 0, 0, 0);
                    acc[yy][0] = __builtin_amdgcn_mfma_f32_16x16x32_f16(al0, Bh.v, acc[yy][0], 0, 0, 0);
                    acc[yy][1] = __builtin_amdgcn_mfma_f32_16x16x32_f16(ah1, Bh.v, acc[yy][1], 0, 0, 0);
                    acc[yy][1] = __builtin_amdgcn_mfma_f32_16x16x32_f16(ah1, Bl.v, acc[yy][1], 0, 0, 0);
                    acc[yy][1] = __builtin_amdgcn_mfma_f32_16x16x32_f16(al1, Bh.v, acc[yy][1], 0, 0, 0);
                }
                #pragma unroll
                for (int m = 0; m < 2; ++m) {
                    f32x4 vv;
                    #pragma unroll
                    for (int r = 0; r < 4; ++r) {
                        float v = fmaxf(acc[0][m][r], acc[1][m][r]);
                        v = fmaxf(v, __shfl_xor(v, 1));
                        vv[r] = fmaxf(v + (m ? cbias1[r] : cbias0[r]), 0.f);
                    }
                    if ((xl & 1) == 0) {
                        const int c = xt * 8 + (xl >> 1) + 1;     // col 1..16
                        const int grp = m * 2 + (g >> 1);
                        const int so = (grp + (c >> 1)) & 3;
                        const int e = (rp * 18 + c) * 32 + so * 8 + (g & 1) * 4;
                        f16x4 h4, l4;
                        #pragma unroll
                        for (int r = 0; r < 4; ++r) {
                            const _Float16 h = (_Float16)vv[r];
                            h4[r] = h;
                            l4[r] = (_Float16)(vv[r] - (float)h);
                        }
                        *(f16x4*)(b1h + e) = h4;
                        *(f16x4*)(b1l + e) = l4;
                    }
                }
            }
        }
        __builtin_amdgcn_s_setprio(0);
    }
    __syncthreads();

    // ---- conv2 (MFMA): rows split, each wave 2 pre-pool rows -> b2 ----
    {
        // zero b3 region (aliases dead sx tail); used two phases later
        for (int i = t; i < 1152; i += 512) ((unsigned*)(region2 + 8192))[i] = 0;

        f32x4 acc[2][2];    // [j][m]
        #pragma unroll
        for (int j = 0; j < 2; ++j)
            #pragma unroll
            for (int m = 0; m < 2; ++m)
                #pragma unroll
                for (int r = 0; r < 4; ++r) acc[j][m][r] = 0.f;

        __builtin_amdgcn_s_setprio(1);
        #pragma unroll
        for (int dy = 0; dy < 3; ++dy) {
            #pragma unroll
            for (int dx = 0; dx < 3; ++dx) {
                const _Float16* wb = w2s + (dy * 3 + dx) * 2048;
                const f16x8 ah0 = *(const f16x8*)(wb + aoff);
                const f16x8 ah1 = *(const f16x8*)(wb + 512 + aoff);
                const f16x8 al0 = *(const f16x8*)(wb + 1024 + aoff);
                const f16x8 al1 = *(const f16x8*)(wb + 1536 + aoff);

                const int cxs = xl + dx;                  // storage col 0..17
                const int so = (g + (cxs >> 1)) & 3;
                #pragma unroll
                for (int j = 0; j < 2; ++j) {
                    const int sy = 2 * w + j + dy - 1;    // wave-uniform
                    if ((unsigned)sy < 16u) {
                        const int e = (sy * 18 + cxs) * 32 + so * 8;
                        const f16x8 bh = *(const f16x8*)(b1h + e);
                        const f16x8 bl = *(const f16x8*)(b1l + e);
                        acc[j][0] = __builtin_amdgcn_mfma_f32_16x16x32_f16(ah0, bh, acc[j][0], 0, 0, 0);
                        acc[j][0] = __builtin_amdgcn_mfma_f32_16x16x32_f16(ah0, bl, acc[j][0], 0, 0, 0);
                        acc[j][0] = __builtin_amdgcn_mfma_f32_16x16x32_f16(al0, bh, acc[j][0], 0, 0, 0);
                        acc[j][1] = __builtin_amdgcn_mfma_f32_16x16x32_f16(ah1, bh, acc[j][1], 0, 0, 0);
                        acc[j][1] = __builtin_amdgcn_mfma_f32_16x16x32_f16(ah1, bl, acc[j][1], 0, 0, 0);
                        acc[j][1] = __builtin_amdgcn_mfma_f32_16x16x32_f16(al1, bh, acc[j][1], 0, 0, 0);
                    }
                }
            }
        }
        __builtin_amdgcn_s_setprio(0);

        // epilogue: pool 2x2 + bias + relu, split fp16 h/l -> b2 [64px][32ic]
        const f32x4 bias0 = *(const f32x4*)(cb2 + g * 4);
        const f32x4 bias1 = *(const f32x4*)(cb2 + 16 + g * 4);
        #pragma unroll
        for (int m = 0; m < 2; ++m) {
            f32x4 vv;
            #pragma unroll
            for (int r = 0; r < 4; ++r) {
                float v = fmaxf(acc[0][m][r], acc[1][m][r]);
                v = fmaxf(v, __shfl_xor(v, 1));
                vv[r] = fmaxf(v + (m ? bias1[r] : bias0[r]), 0.f);
            }
            if ((lane & 1) == 0) {
                const int pp = w * 8 + (xl >> 1);         // pooled px 0..63
                const int slot = m * 2 + (g >> 1);
                const int so2 = (slot + (pp >> 1)) & 3;
                const int e = pp * 32 + so2 * 8 + (g & 1) * 4;
                f16x4 h4, l4;
                #pragma unroll
                for (int r = 0; r < 4; ++r) {
                    const _Float16 h = (_Float16)vv[r];
                    h4[r] = h;
                    l4[r] = (_Float16)(vv[r] - (float)h);
                }
                *(f16x4*)(b2h + e) = h4;
                *(f16x4*)(b2l + e) = l4;
            }
        }
    }
    __syncthreads();

    // ---- conv3 (MFMA, oc-split): wave pair (wr,mh) -> b3 padded ----
    {
        const int p = wr * 16 + xl;          // pre-pool pixel 0..63
        const int py3 = p >> 3, px3 = p & 7;
        f32x4 acc;
        #pragma unroll
        for (int r = 0; r < 4; ++r) acc[r] = 0.f;

        __builtin_amdgcn_s_setprio(1);
        #pragma unroll
        for (int dy = 0; dy < 3; ++dy) {
            #pragma unroll
            for (int dx = 0; dx < 3; ++dx) {
                const _Float16* wb = w3s + (dy * 3 + dx) * 2048 + mh * 512;
                const f16x8 ah = *(const f16x8*)(wb + aoff);
                const f16x8 al = *(const f16x8*)(wb + 1024 + aoff);

                const int syL = py3 + dy - 1, sxL = px3 + dx - 1;
                const bool ok = ((unsigned)syL < 8u) && ((unsigned)sxL < 8u);
                const int cy = syL < 0 ? 0 : (syL > 7 ? 7 : syL);
                const int cx = sxL < 0 ? 0 : (sxL > 7 ? 7 : sxL);
                const int cp = cy * 8 + cx;
                const int so = (g + (cp >> 1)) & 3;
                const int e = cp * 32 + so * 8;
                f16x8 bh = *(const f16x8*)(b2h + e);
                f16x8 bl = *(const f16x8*)(b2l + e);
                if (!ok) { bh = f16x8_zero(); bl = f16x8_zero(); }
                acc = __builtin_amdgcn_mfma_f32_16x16x32_f16(ah, bh, acc, 0, 0, 0);
                acc = __builtin_amdgcn_mfma_f32_16x16x32_f16(ah, bl, acc, 0, 0, 0);
                acc = __builtin_amdgcn_mfma_f32_16x16x32_f16(al, bh, acc, 0, 0, 0);
            }
        }
        __builtin_amdgcn_s_setprio(0);

        const f32x4 bias = *(const f32x4*)(cb3 + mh * 16 + g * 4);
        f32x4 vv;
        #pragma unroll
        for (int r = 0; r < 4; ++r) {
            float v = acc[r];
            v = fmaxf(v, __shfl_xor(v, 1));
            v = fmaxf(v, __shfl_xor(v, 8));
            vv[r] = fmaxf(v + bias[r], 0.f);
        }
        if ((lane & 9) == 0) {     // x even, y even
            const int yr = wr;                 // pooled row 0..3
            const int xr = (xl & 7) >> 1;      // pooled col 0..3
            const int pp3 = (yr + 1) * 6 + (xr + 1);
            const int grp = mh * 2 + (g >> 1);
            const int so = (grp + (pp3 >> 1)) & 3;
            const int e = pp3 * 32 + so * 8 + (g & 1) * 4;
            f16x4 h4, l4;
            #pragma unroll
            for (int r = 0; r < 4; ++r) {
                const _Float16 h = (_Float16)vv[r];
                h4[r] = h;
                l4[r] = (_Float16)(vv[r] - (float)h);
            }
            *(f16x4*)(b3h + e) = h4;
            *(f16x4*)(b3l + e) = l4;
        }
    }
    __syncthreads();

    // ---- conv4 (MFMA, tap+oc split): taps {wr,wr+4,wr+8}, half mh ----
    {
        f32x4 a4;
        #pragma unroll
        for (int r = 0; r < 4; ++r) a4[r] = 0.f;

        __builtin_amdgcn_s_setprio(1);
        for (int t9 = wr; t9 < 9; t9 += 4) {
            const _Float16* wb = w4s + t9 * 2048 + mh * 512;
            const f16x8 ah = *(const f16x8*)(wb + aoff);
            const f16x8 al = *(const f16x8*)(wb + 1024 + aoff);
            const int dy = t9 / 3, dx = t9 - dy * 3;
            const int pp3 = ((xl >> 2) + dy) * 6 + (xl & 3) + dx;
            const int so = (g + (pp3 >> 1)) & 3;
            const int e = pp3 * 32 + so * 8;
            const f16x8 bh = *(const f16x8*)(b3h + e);
            const f16x8 bl = *(const f16x8*)(b3l + e);
            a4 = __builtin_amdgcn_mfma_f32_16x16x32_f16(ah, bh, a4, 0, 0, 0);
            a4 = __builtin_amdgcn_mfma_f32_16x16x32_f16(ah, bl, a4, 0, 0, 0);
            a4 = __builtin_amdgcn_mfma_f32_16x16x32_f16(al, bh, a4, 0, 0, 0);
        }
        __builtin_amdgcn_s_setprio(0);
        *(f32x4*)(scr + (w * 64 + lane) * 4) = a4;
        __syncthreads();

        if (w < 2) {     // wave 0 reduces mh=0, wave 1 reduces mh=1
            f32x4 r0;
            #pragma unroll
            for (int r = 0; r < 4; ++r) r0[r] = 0.f;
            #pragma unroll
            for (int k = 0; k < 4; ++k) {
                const f32x4 p0 = *(const f32x4*)(scr + ((k * 2 + w) * 64 + lane) * 4);
                #pragma unroll
                for (int r = 0; r < 4; ++r) r0[r] += p0[r];
            }
            const f32x4 bias = *(const f32x4*)(cb4 + w * 16 + g * 4);
            const int y = xl >> 2, xx = xl & 3;
            f32x4 vv;
            #pragma unroll
            for (int r = 0; r < 4; ++r) {
                float v = r0[r];
                v = fmaxf(v, __shfl_xor(v, 1));
                v = fmaxf(v, __shfl_xor(v, 4));
                vv[r] = fmaxf(v + bias[r], 0.f);
            }
            if ((xl & 5) == 0) {       // x even, y even
                const int oc0 = w * 16 + g * 4;
                #pragma unroll
                for (int r = 0; r < 4; ++r)
                    t4[(size_t)b * 128 + (oc0 + r) * 4 + (y >> 1) * 2 + (xx >> 1)] = vv[r];
            }
        }
    }
}

// ---------------- BN batch stats, stage A: 256 blocks of partials ----------
__global__ __launch_bounds__(256) void bnstatsA_kernel(
    const float* __restrict__ t4, double* __restrict__ part)
{
    __shared__ double ssum[256];
    __shared__ double ssq[256];
    const int c = blockIdx.x >> 3, s = blockIdx.x & 7, t = threadIdx.x;
    const float* base = t4 + (size_t)s * 512 * 128 + c * 4;
    double sm = 0.0, q = 0.0;
    for (int j = t; j < 2048; j += 256) {
        const float v = base[(size_t)(j >> 2) * 128 + (j & 3)];
        sm += (double)v;
        q += (double)v * (double)v;
    }
    ssum[t] = sm; ssq[t] = q;
    __syncthreads();
    for (int w = 128; w > 0; w >>= 1) {
        if (t < w) { ssum[t] += ssum[t + w]; ssq[t] += ssq[t + w]; }
        __syncthreads();
    }
    if (t == 0) {
        part[(c * 8 + s) * 2]     = ssum[0];
        part[(c * 8 + s) * 2 + 1] = ssq[0];
    }
}

// ---------------- BN batch stats, stage B: reduce 8 partials/channel -------
__global__ __launch_bounds__(256) void bnstatsB_kernel(
    const double* __restrict__ part, float* __restrict__ mus, float* __restrict__ rss)
{
    const int t = threadIdx.x;               // c = t>>3, s = t&7 (8-lane groups)
    double sm = part[t * 2], q = part[t * 2 + 1];
    #pragma unroll
    for (int d = 1; d < 8; d <<= 1) {
        sm += __shfl_xor(sm, d);
        q += __shfl_xor(q, d);
    }
    if ((t & 7) == 0) {
        const double mu = sm / 16384.0;
        const double var = q / 16384.0 - mu * mu;
        mus[t >> 3] = (float)mu;
        rss[t >> 3] = (float)(1.0 / sqrt(var + 1e-5));
    }
}

// ---------------- routing: 4 samples/block, wave-synchronous ---------------
__device__ __forceinline__ int wave_argmax16(double v, int idx) {
    #pragma unroll
    for (int d = 8; d >= 1; d >>= 1) {
        const double ov = __shfl_xor(v, d);
        const int oi = __shfl_xor(idx, d);
        if (ov > v || (ov == v && oi < idx)) { v = ov; idx = oi; }
    }
    return __shfl(idx, 0);
}

__global__ __launch_bounds__(256) void routing_kernel(
    const float* __restrict__ t4, const float* __restrict__ mus,
    const float* __restrict__ rss,
    const float* __restrict__ bng, const float* __restrict__ bnb,
    const float* __restrict__ wpt, const float* __restrict__ wd1,
    const float* __restrict__ wd2, const float* __restrict__ wd3,
    const float* __restrict__ s1w, const float* __restrict__ s1b,
    const float* __restrict__ s2w, const float* __restrict__ s2b,
    const float* __restrict__ s3w, const float* __restrict__ s3b,
    float* __restrict__ out)
{
    __shared__ float fs[4][128];
    __shared__ float h1s[4][48];
    __shared__ float h2s[4][48];
    const int t = threadIdx.x & 63;
    const int w = threadIdx.x >> 6;
    const int b = blockIdx.x * 4 + w;
    float* fw  = fs[w];
    float* h1w = h1s[w];
    float* h2w = h2s[w];

    for (int i = t; i < 128; i += 64) {
        const int c = i >> 2;
        const float v = t4[(size_t)b * 128 + i];
        fw[i] = (v - mus[c]) * rss[c] * bng[c] + bnb[c];
    }
    __builtin_amdgcn_wave_barrier();

    // task assignment: argmax over 10 agents (fp64, 4-wide unroll)
    double a = -INFINITY;
    if (t < 10) {
        double s0 = 0, s1 = 0, s2 = 0, s3 = 0;
        for (int k = 0; k < 128; k += 4) {
            s0 = fma((double)fw[k],     (double)wpt[k * 10 + t],       s0);
            s1 = fma((double)fw[k + 1], (double)wpt[(k + 1) * 10 + t], s1);
            s2 = fma((double)fw[k + 2], (double)wpt[(k + 2) * 10 + t], s2);
            s3 = fma((double)fw[k + 3], (double)wpt[(k + 3) * 10 + t], s3);
        }
        a = (s0 + s1) + (s2 + s3);
    }
    const int agent = wave_argmax16(a, t & 15);

    // decision 1
    a = -INFINITY;
    if (t < 16) {
        const float* wd = wd1 + (size_t)agent * 2048 + t;
        double s0 = 0, s1 = 0, s2 = 0, s3 = 0;
        for (int k = 0; k < 128; k += 4) {
            s0 = fma((double)fw[k],     (double)wd[k * 16],       s0);
            s1 = fma((double)fw[k + 1], (double)wd[(k + 1) * 16], s1);
            s2 = fma((double)fw[k + 2], (double)wd[(k + 2) * 16], s2);
            s3 = fma((double)fw[k + 3], (double)wd[(k + 3) * 16], s3);
        }
        a = (s0 + s1) + (s2 + s3);
    }
    const int a1 = wave_argmax16(a, t & 15);

    // expert layer 1: 128 -> 48, relu
    if (t < 48) {
        const float* wd = s1w + (size_t)a1 * 6144 + t;
        float c0 = s1b[a1 * 48 + t], c1 = 0.f, c2 = 0.f, c3 = 0.f;
        for (int k = 0; k < 128; k += 4) {
            c0 = fmaf(fw[k],     wd[k * 48],       c0);
            c1 = fmaf(fw[k + 1], wd[(k + 1) * 48], c1);
            c2 = fmaf(fw[k + 2], wd[(k + 2) * 48], c2);
            c3 = fmaf(fw[k + 3], wd[(k + 3) * 48], c3);
        }
        h1w[t] = fmaxf((c0 + c1) + (c2 + c3), 0.f);
    }
    __builtin_amdgcn_wave_barrier();

    // decision 2
    a = -INFINITY;
    if (t < 16) {
        const float* wd = wd2 + (size_t)agent * 768 + t;
        double s0 = 0, s1 = 0, s2 = 0, s3 = 0;
        for (int k = 0; k < 48; k += 4) {
            s0 = fma((double)h1w[k],     (double)wd[k * 16],       s0);
            s1 = fma((double)h1w[k + 1], (double)wd[(k + 1) * 16], s1);
            s2 = fma((double)h1w[k + 2], (double)wd[(k + 2) * 16], s2);
            s3 = fma((double)h1w[k + 3], (double)wd[(k + 3) * 16], s3);
        }
        a = (s0 + s1) + (s2 + s3);
    }
    const int a2 = wave_argmax16(a, t & 15);

    // expert layer 2: 48 -> 48, relu
    if (t < 48) {
        const float* wd = s2w + (size_t)a2 * 2304 + t;
        float c0 = s2b[a2 * 48 + t], c1 = 0.f, c2 = 0.f, c3 = 0.f;
        for (int k = 0; k < 48; k += 4) {
            c0 = fmaf(h1w[k],     wd[k * 48],       c0);
            c1 = fmaf(h1w[k + 1], wd[(k + 1) * 48], c1);
            c2 = fmaf(h1w[k + 2], wd[(k + 2) * 48], c2);
            c3 = fmaf(h1w[k + 3], wd[(k + 3) * 48], c3);
        }
        h2w[t] = fmaxf((c0 + c1) + (c2 + c3), 0.f);
    }
    __builtin_amdgcn_wave_barrier();

    // decision 3
    a = -INFINITY;
    if (t < 16) {
        const float* wd = wd3 + (size_t)agent * 768 + t;
        double s0 = 0, s1 = 0, s2 = 0, s3 = 0;
        for (int k = 0; k < 48; k += 4) {
            s0 = fma((double)h2w[k],     (double)wd[k * 16],       s0);
            s1 = fma((double)h2w[k + 1], (double)wd[(k + 1) * 16], s1);
            s2 = fma((double)h2w[k + 2], (double)wd[(k + 2) * 16], s2);
            s3 = fma((double)h2w[k + 3], (double)wd[(k + 3) * 16], s3);
        }
        a = (s0 + s1) + (s2 + s3);
    }
    const int a3 = wave_argmax16(a, t & 15);

    // expert layer 3: 48 -> 10, no relu
    if (t < 10) {
        const float* wd = s3w + (size_t)a3 * 480 + t;
        float c0 = s3b[a3 * 10 + t], c1 = 0.f, c2 = 0.f, c3 = 0.f;
        for (int k = 0; k < 48; k += 4) {
            c0 = fmaf(h2w[k],     wd[k * 10],       c0);
            c1 = fmaf(h2w[k + 1], wd[(k + 1) * 10], c1);
            c2 = fmaf(h2w[k + 2], wd[(k + 2) * 10], c2);
            c3 = fmaf(h2w[k + 3], wd[(k + 3) * 10], c3);
        }
        out[(size_t)b * 10 + t] = (c0 + c1) + (c2 + c3);
    }
}

// ---------------------------------------------------------------------------
extern "C" void kernel_launch(void* const* d_in, const int* in_sizes, int n_in,
                              void* d_out, int out_size, void* d_ws, size_t ws_size,
                              hipStream_t stream)
{
    (void)in_sizes; (void)n_in; (void)out_size; (void)ws_size;

    const float* x   = (const float*)d_in[0];
    const float* cw1 = (const float*)d_in[2];
    const float* cb1 = (const float*)d_in[3];
    const float* cw2 = (const float*)d_in[4];
    const float* cb2 = (const float*)d_in[5];
    const float* cw3 = (const float*)d_in[6];
    const float* cb3 = (const float*)d_in[7];
    const float* cw4 = (const float*)d_in[8];
    const float* cb4 = (const float*)d_in[9];
    const float* bng = (const float*)d_in[10];
    const float* bnb = (const float*)d_in[11];
    const float* wpt = (const float*)d_in[12];
    const float* wd1 = (const float*)d_in[13];
    const float* wd2 = (const float*)d_in[14];
    const float* wd3 = (const float*)d_in[15];
    const float* s1w = (const float*)d_in[16];
    const float* s1b = (const float*)d_in[17];
    const float* s2w = (const float*)d_in[18];
    const float* s2b = (const float*)d_in[19];
    const float* s3w = (const float*)d_in[20];
    const float* s3b = (const float*)d_in[21];
    float* out = (float*)d_out;

    float* t4  = (float*)d_ws;                       // [4096][128]
    float* mus = t4 + (size_t)IMG_B * 128;           // 32
    float* rss = mus + 32;                           // 32
    _Float16* w1s = (_Float16*)(rss + 32);           // 2048 f16
    _Float16* w2s = w1s + 2048;                      // 18432 f16
    _Float16* w3s = w2s + 18432;                     // 18432 f16
    _Float16* w4s = w3s + 18432;                     // 18432 f16
    double* part = (double*)(w4s + 18432);           // 512 doubles

    hipLaunchKernelGGL(twt_kernel, dim3(36), dim3(256), 0, stream,
                       cw1, cw2, cw3, cw4, w1s, w2s, w3s, w4s);
    hipLaunchKernelGGL(backbone_kernel, dim3(IMG_B), dim3(512), 0, stream,
                       x, w1s, cb1, w2s, cb2, w3s, cb3, w4s, cb4, t4);
    hipLaunchKernelGGL(bnstatsA_kernel, dim3(256), dim3(256), 0, stream, t4, part);
    hipLaunchKernelGGL(bnstatsB_kernel, dim3(1), dim3(256), 0, stream, part, mus, rss);
    hipLaunchKernelGGL(routing_kernel, dim3(IMG_B / 4), dim3(256), 0, stream,
                       t4, mus, rss, bng, bnb, wpt, wd1, wd2, wd3,
                       s1w, s1b, s2w, s2b, s3w, s3b, out);
}